// Round 11
// baseline (318.203 us; speedup 1.0000x reference)
//
#include <hip/hip_runtime.h>

#define N_NODES 10000
#define D 128
#define N_EDGES 640000
#define NBLK 256               // persistent blocks (1 per CU)
#define NTHR 512               // threads per block (8 waves)
#define EPB (N_EDGES / NBLK)   // 2500 edges per block
#define SB 40                  // scan blocks (lookback)
#define NPSB 250               // nodes per scan block
#define NWAVES (NBLK * (NTHR / 64))   // 2048 waves

typedef __attribute__((ext_vector_type(8))) short bf16x8;          // MFMA A/B frag
typedef __attribute__((ext_vector_type(4))) float f32x4;           // MFMA acc
typedef __attribute__((ext_vector_type(8))) unsigned short us8;    // 16B bf16 chunk
typedef __attribute__((ext_vector_type(8))) float f32x8;

__device__ __forceinline__ unsigned short f2bf(float f) {
    union { float f; unsigned int i; } v;
    v.f = f;
    unsigned int b = v.i;
    unsigned int rounded = b + 0x7fffu + ((b >> 16) & 1u);  // RNE
    return (unsigned short)(rounded >> 16);
}

__device__ __forceinline__ float bf2f(unsigned short u) {
    union { unsigned int i; float f; } v;
    v.i = ((unsigned int)u) << 16;
    return v.f;
}

__device__ __forceinline__ f32x8 bf2f8(us8 v) {
    f32x8 r;
#pragma unroll
    for (int t = 0; t < 8; ++t) r[t] = bf2f(v[t]);
    return r;
}

// grid barrier: counter pre-zeroed by hipMemsetAsync; target = epoch*NBLK.
// agent-scope fences handle cross-XCD L2 (wb/inv cache ops, same as grid.sync()).
__device__ __forceinline__ void gbar(unsigned int* bar, unsigned int target) {
    __syncthreads();
    if (threadIdx.x == 0) {
        __builtin_amdgcn_fence(__ATOMIC_RELEASE, "agent");
        __hip_atomic_fetch_add(bar, 1u, __ATOMIC_ACQ_REL, __HIP_MEMORY_SCOPE_AGENT);
        while (__hip_atomic_load(bar, __ATOMIC_ACQUIRE, __HIP_MEMORY_SCOPE_AGENT) < target)
            __builtin_amdgcn_s_sleep(2);
        __builtin_amdgcn_fence(__ATOMIC_ACQUIRE, "agent");
    }
    __syncthreads();
}

__global__ __launch_bounds__(NTHR) void sage_mega_kernel(
        const float* __restrict__ x, const int* __restrict__ ei,
        const float* __restrict__ Wl, const float* __restrict__ bl,
        const float* __restrict__ Wr, float* __restrict__ out,
        unsigned long long* __restrict__ flags,   // [0..39] lookback; bar at +48
        int* __restrict__ row_start,
        unsigned short* __restrict__ cnt,         // NBLK * N_NODES
        unsigned short* __restrict__ lrank,
        unsigned short* __restrict__ csr,
        unsigned short* __restrict__ xh,
        unsigned short* __restrict__ aggb,
        unsigned short* __restrict__ Wlb,
        unsigned short* __restrict__ Wrb) {
    __shared__ int h[N_NODES];                    // 40 KB; reused as sc[] in P2
    unsigned int* bar = (unsigned int*)(flags + 48);
    const int tid = threadIdx.x;
    const int b = blockIdx.x;
    const int gid = b * NTHR + tid;               // 131072 global threads

    // ---------------- P1: cast x/W to bf16 + per-block LDS histogram ----------------
    for (int n = tid; n < N_NODES; n += NTHR) h[n] = 0;

    const float4* x4 = (const float4*)x;
    ushort4* xh4 = (ushort4*)xh;
    for (int i = gid; i < N_NODES * D / 4; i += NBLK * NTHR) {
        float4 v = x4[i];
        ushort4 o;
        o.x = f2bf(v.x); o.y = f2bf(v.y); o.z = f2bf(v.z); o.w = f2bf(v.w);
        xh4[i] = o;
    }
    if (gid < D * D / 4) {
        float4 a = ((const float4*)Wl)[gid], c = ((const float4*)Wr)[gid];
        ushort4 oa, oc;
        oa.x = f2bf(a.x); oa.y = f2bf(a.y); oa.z = f2bf(a.z); oa.w = f2bf(a.w);
        oc.x = f2bf(c.x); oc.y = f2bf(c.y); oc.z = f2bf(c.z); oc.w = f2bf(c.w);
        ((ushort4*)Wlb)[gid] = oa;
        ((ushort4*)Wrb)[gid] = oc;
    }
    __syncthreads();

    const int ebase = b * EPB;
    for (int e = ebase + tid; e < ebase + EPB; e += NTHR) {
        int d = ei[N_EDGES + e];
        lrank[e] = (unsigned short)atomicAdd(&h[d], 1);
    }
    __syncthreads();
    {
        unsigned short* c = cnt + (size_t)b * N_NODES;
        for (int n = tid; n < N_NODES; n += NTHR) c[n] = (unsigned short)h[n];
    }

    gbar(bar, 1 * NBLK);

    // ---------------- P2: column scan + node scan (lookback among 40 blocks) --------
    {
        int* sc = h;                               // reuse LDS
        int deg = 0;
        const int n = b * NPSB + tid;
        if (b < SB && tid < NPSB) {
            int s = 0;
#pragma unroll 8
            for (int j = 0; j < NBLK; ++j) {
                int idx = j * N_NODES + n;
                int v = cnt[idx];
                cnt[idx] = (unsigned short)s;
                s += v;
            }
            deg = s;
        }
        if (b < SB) {
            if (tid < 256) sc[tid] = (tid < NPSB) ? deg : 0;
            __syncthreads();
            for (int off = 1; off < 256; off <<= 1) {
                int v = 0;
                if (tid < 256 && tid >= off) v = sc[tid - off];
                __syncthreads();
                if (tid < 256) sc[tid] += v;
                __syncthreads();
            }
            const int total = sc[255];
            const int local_excl = (tid < 256) ? (sc[tid] - deg) : 0;
            __syncthreads();
            if (tid == 0) {
                int excl = 0;
                if (b == 0) {
                    __hip_atomic_store(&flags[0], (2ULL << 32) | (unsigned)total,
                                       __ATOMIC_RELEASE, __HIP_MEMORY_SCOPE_AGENT);
                } else {
                    __hip_atomic_store(&flags[b], (1ULL << 32) | (unsigned)total,
                                       __ATOMIC_RELEASE, __HIP_MEMORY_SCOPE_AGENT);
                    int j = b - 1;
                    while (j >= 0) {
                        unsigned long long f = __hip_atomic_load(&flags[j], __ATOMIC_ACQUIRE,
                                                                 __HIP_MEMORY_SCOPE_AGENT);
                        unsigned st = (unsigned)(f >> 32);
                        if (st == 0) continue;
                        excl += (int)(unsigned)(f & 0xffffffffULL);
                        if (st == 2) break;
                        --j;
                    }
                    __hip_atomic_store(&flags[b], (2ULL << 32) | (unsigned)(excl + total),
                                       __ATOMIC_RELEASE, __HIP_MEMORY_SCOPE_AGENT);
                }
                sc[256] = excl;
            }
            __syncthreads();
            if (tid < NPSB) row_start[n] = sc[256] + local_excl;
            if (b == SB - 1 && tid == 0) row_start[N_NODES] = N_EDGES;
        }
    }

    gbar(bar, 2 * NBLK);

    // ---------------- P3: atomic-free scatter ----------------
    {
        const unsigned short* cb = cnt + (size_t)b * N_NODES;
        for (int i = ebase + tid; i < ebase + EPB; i += NTHR) {
            int s = ei[i];
            int d = ei[N_EDGES + i];
            int pos = row_start[d] + (int)cb[d] + (int)lrank[i];
            csr[pos] = (unsigned short)s;
        }
    }

    gbar(bar, 3 * NBLK);

    // ---------------- P4: wave-per-node mean aggregation ----------------
    {
        const us8* xh8 = (const us8*)xh;
        us8* aggb8 = (us8*)aggb;
        const int wave = tid >> 6;
        const int lane = tid & 63;
        const int slot = lane >> 4;        // 0..3
        const int lane16 = lane & 15;      // feature octet
        const int gw = b * (NTHR / 64) + wave;   // 0..2047

        for (int node = gw; node < N_NODES; node += NWAVES) {
            const int start = row_start[node];
            const int end = row_start[node + 1];
            f32x8 a0 = 0.f, a1 = 0.f, a2 = 0.f, a3 = 0.f;
            int j = start + slot;
            for (; j + 12 < end; j += 16) {
                int i0 = csr[j], i1 = csr[j + 4], i2 = csr[j + 8], i3 = csr[j + 12];
                us8 v0 = xh8[i0 * 16 + lane16];
                us8 v1 = xh8[i1 * 16 + lane16];
                us8 v2 = xh8[i2 * 16 + lane16];
                us8 v3 = xh8[i3 * 16 + lane16];
                a0 += bf2f8(v0); a1 += bf2f8(v1); a2 += bf2f8(v2); a3 += bf2f8(v3);
            }
            for (; j < end; j += 4) a0 += bf2f8(xh8[(int)csr[j] * 16 + lane16]);
            a0 = (a0 + a1) + (a2 + a3);
            // reduce across 4 slots (lanes xor 16, 32)
#pragma unroll
            for (int c = 0; c < 8; ++c) {
                float v = a0[c];
                v += __shfl_xor(v, 16, 64);
                v += __shfl_xor(v, 32, 64);
                a0[c] = v;
            }
            if (slot == 0) {
                int cntE = end - start;
                float inv = (cntE > 0) ? 1.0f / (float)cntE : 0.0f;
                us8 pack;
#pragma unroll
                for (int t = 0; t < 8; ++t) pack[t] = f2bf(a0[t] * inv);
                aggb8[node * 16 + lane16] = pack;
            }
        }
    }

    gbar(bar, 4 * NBLK);

    // ---------------- P5: SAGE linear + residual via bf16 MFMA ----------------
    {
        const int wave = tid >> 6;
        const int lane = tid & 63;
        const int l15 = lane & 15;
        const int quad = lane >> 4;
        const int gw = b * (NTHR / 64) + wave;

        for (int t = gw; t < 625 * 8; t += NWAVES) {
            const int mt = t >> 3;           // M-tile 0..624
            const int ft = t & 7;            // F-tile 0..7
            const int row0 = mt * 16;
            const int out0 = ft * 16;
            const int m = row0 + l15;
            const int f = out0 + l15;

            const bf16x8* arow = (const bf16x8*)(aggb + (size_t)m * D) + quad;
            const bf16x8* xrow = (const bf16x8*)(xh   + (size_t)m * D) + quad;
            const bf16x8* wlro = (const bf16x8*)(Wlb + (size_t)f * D) + quad;
            const bf16x8* wrro = (const bf16x8*)(Wrb + (size_t)f * D) + quad;

            f32x4 c = {0.f, 0.f, 0.f, 0.f};
#pragma unroll
            for (int kk = 0; kk < 4; ++kk) {
                c = __builtin_amdgcn_mfma_f32_16x16x32_bf16(arow[kk * 4], wlro[kk * 4], c, 0, 0, 0);
                c = __builtin_amdgcn_mfma_f32_16x16x32_bf16(xrow[kk * 4], wrro[kk * 4], c, 0, 0, 0);
            }

            const float bias = bl[f];
#pragma unroll
            for (int r = 0; r < 4; ++r) {
                int row = row0 + quad * 4 + r;
                int idx = row * D + f;
                out[idx] = x[idx] + bias + c[r];
            }
        }
    }
}

extern "C" void kernel_launch(void* const* d_in, const int* in_sizes, int n_in,
                              void* d_out, int out_size, void* d_ws, size_t ws_size,
                              hipStream_t stream) {
    const float* x  = (const float*)d_in[0];
    const int*   ei = (const int*)d_in[1];     // [2, E] int32
    const float* Wl = (const float*)d_in[2];
    const float* bl = (const float*)d_in[3];
    const float* Wr = (const float*)d_in[4];
    float* out = (float*)d_out;

    // workspace layout (16B-aligned segments)
    unsigned long long* flags = (unsigned long long*)d_ws;               // 64 ULL (512 B)
    int* row_start = (int*)(flags + 64);                                 // 10016 ints
    unsigned short* cnt   = (unsigned short*)(row_start + 10016);        // NBLK*N_NODES
    unsigned short* lrank = cnt + (size_t)NBLK * N_NODES;                // N_EDGES
    unsigned short* csr   = lrank + N_EDGES;                             // N_EDGES
    unsigned short* xh    = csr + N_EDGES;                               // N_NODES*D bf16
    unsigned short* aggb  = xh + (size_t)N_NODES * D;                    // N_NODES*D bf16
    unsigned short* Wlb   = aggb + (size_t)N_NODES * D;                  // D*D bf16
    unsigned short* Wrb   = Wlb + D * D;                                 // D*D bf16

    // zero barrier counter + lookback flags (ws is poisoned 0xAA before every launch)
    (void)hipMemsetAsync(flags, 0, 512, stream);

    sage_mega_kernel<<<NBLK, NTHR, 0, stream>>>(x, ei, Wl, bl, Wr, out,
                                                flags, row_start, cnt, lrank, csr,
                                                xh, aggb, Wlb, Wrb);
}

// Round 12
// 122.547 us; speedup vs baseline: 2.5966x; 2.5966x over previous
//
#include <hip/hip_runtime.h>

#define N_NODES 10000
#define D 128
#define N_EDGES 640000
#define NB 256                 // histogram blocks
#define HTHR 512               // hist threads
#define EPB (N_EDGES / NB)     // 2500 edges per block
#define SB 40                  // scan blocks (lookback)
#define NPSB 250               // nodes per scan block

typedef __attribute__((ext_vector_type(8))) short bf16x8;          // MFMA A/B frag
typedef __attribute__((ext_vector_type(4))) float f32x4;           // MFMA acc
typedef __attribute__((ext_vector_type(8))) unsigned short us8;    // 16B bf16 chunk
typedef __attribute__((ext_vector_type(8))) float f32x8;

__device__ __forceinline__ unsigned short f2bf(float f) {
    union { float f; unsigned int i; } v;
    v.f = f;
    unsigned int b = v.i;
    unsigned int rounded = b + 0x7fffu + ((b >> 16) & 1u);  // RNE
    return (unsigned short)(rounded >> 16);
}

__device__ __forceinline__ float bf2f(unsigned short u) {
    union { unsigned int i; float f; } v;
    v.i = ((unsigned int)u) << 16;
    return v.f;
}

__device__ __forceinline__ f32x8 bf2f8(us8 v) {
    f32x8 r;
#pragma unroll
    for (int t = 0; t < 8; ++t) r[t] = bf2f(v[t]);
    return r;
}

// ---------------- P1: cast x/W to bf16 + per-block LDS histogram ----------------

__global__ __launch_bounds__(HTHR) void hist_cast_kernel(const int* __restrict__ ei,
                                                         const float4* __restrict__ x4,
                                                         const float4* __restrict__ Wl4,
                                                         const float4* __restrict__ Wr4,
                                                         ushort4* __restrict__ xh4,
                                                         ushort4* __restrict__ Wlb4,
                                                         ushort4* __restrict__ Wrb4,
                                                         unsigned short* __restrict__ lrank,
                                                         unsigned short* __restrict__ cnt,
                                                         unsigned long long* __restrict__ flags) {
    __shared__ int h[N_NODES];
    const int tid = threadIdx.x;
    const int b = blockIdx.x;
    for (int n = tid; n < N_NODES; n += HTHR) h[n] = 0;
    if (b == 0 && tid < SB) flags[tid] = 0ULL;

    const int gid = b * HTHR + tid;                 // 131072 threads
    for (int i = gid; i < N_NODES * D / 4; i += NB * HTHR) {
        float4 v = x4[i];
        ushort4 o;
        o.x = f2bf(v.x); o.y = f2bf(v.y); o.z = f2bf(v.z); o.w = f2bf(v.w);
        xh4[i] = o;
    }
    if (gid < D * D / 4) {
        float4 a = Wl4[gid], c = Wr4[gid];
        ushort4 oa, oc;
        oa.x = f2bf(a.x); oa.y = f2bf(a.y); oa.z = f2bf(a.z); oa.w = f2bf(a.w);
        oc.x = f2bf(c.x); oc.y = f2bf(c.y); oc.z = f2bf(c.z); oc.w = f2bf(c.w);
        Wlb4[gid] = oa;
        Wrb4[gid] = oc;
    }
    __syncthreads();

    const int base = b * EPB;
    for (int e = base + tid; e < base + EPB; e += HTHR) {
        int d = ei[N_EDGES + e];                    // row 1 = dst
        lrank[e] = (unsigned short)atomicAdd(&h[d], 1);
    }
    __syncthreads();
    unsigned short* c = cnt + (size_t)b * N_NODES;
    for (int n = tid; n < N_NODES; n += HTHR) c[n] = (unsigned short)h[n];
}

// ---------------- P2: column scan + node scan (wave-parallel lookback) ----------

__global__ __launch_bounds__(256) void colscan_scan_kernel(unsigned short* __restrict__ cnt,
                                                           int* __restrict__ row_start,
                                                           unsigned long long* __restrict__ flags) {
    const int t = threadIdx.x;
    const int b = blockIdx.x;
    const int n = b * NPSB + t;            // valid for t < NPSB
    __shared__ int sc[258];

    int deg = 0;
    if (t < NPSB) {
        int s = 0;
#pragma unroll 16
        for (int j = 0; j < NB; ++j) {
            int idx = j * N_NODES + n;
            int v = cnt[idx];
            cnt[idx] = (unsigned short)s;  // exclusive prefix within column
            s += v;
        }
        deg = s;
    }
    sc[t] = deg;
    __syncthreads();
    for (int off = 1; off < 256; off <<= 1) {
        int v = (t >= off) ? sc[t - off] : 0;
        __syncthreads();
        sc[t] += v;
        __syncthreads();
    }
    const int total = sc[255];
    const int local_excl = sc[t] - deg;
    __syncthreads();

    if (b == 0) {
        if (t == 0) {
            __hip_atomic_store(&flags[0], (2ULL << 32) | (unsigned)total,
                               __ATOMIC_RELEASE, __HIP_MEMORY_SCOPE_AGENT);
            sc[256] = 0;
        }
    } else {
        if (t == 0) {
            __hip_atomic_store(&flags[b], (1ULL << 32) | (unsigned)total,
                               __ATOMIC_RELEASE, __HIP_MEMORY_SCOPE_AGENT);
        }
        if (t < 64) {                      // wave 0: parallel lookback
            const unsigned long long mask_b = (1ULL << b) - 1;   // b <= 39 < 64
            int excl;
            for (;;) {
                unsigned long long f = (t < b)
                    ? __hip_atomic_load(&flags[t], __ATOMIC_ACQUIRE, __HIP_MEMORY_SCOPE_AGENT)
                    : (2ULL << 32);
                unsigned st = (unsigned)(f >> 32);
                unsigned long long ready = __ballot(st >= 1);
                if ((ready & mask_b) == mask_b) {
                    unsigned long long b2 = __ballot(st == 2) & mask_b;   // bit0 set (block 0 is st2)
                    int j = 63 - __builtin_clzll(b2 | 1ULL);              // highest st2 index
                    int v = (t >= j && t < b) ? (int)(unsigned)(f & 0xffffffffULL) : 0;
#pragma unroll
                    for (int off = 32; off > 0; off >>= 1) v += __shfl_down(v, off, 64);
                    excl = __shfl(v, 0, 64);
                    break;
                }
            }
            if (t == 0) {
                __hip_atomic_store(&flags[b], (2ULL << 32) | (unsigned)(excl + total),
                                   __ATOMIC_RELEASE, __HIP_MEMORY_SCOPE_AGENT);
                sc[256] = excl;
            }
        }
    }
    __syncthreads();
    if (t < NPSB) row_start[n] = sc[256] + local_excl;
    if (b == SB - 1 && t == 0) row_start[N_NODES] = N_EDGES;
}

// ---------------- P3: atomic-free scatter ----------------

__global__ __launch_bounds__(256) void scatter_kernel(const int* __restrict__ ei,
                                                      const int* __restrict__ row_start,
                                                      const unsigned short* __restrict__ cnt,
                                                      const unsigned short* __restrict__ lrank,
                                                      unsigned short* __restrict__ csr) {
    int i = blockIdx.x * 256 + threadIdx.x;
    if (i < N_EDGES) {
        int b = i / EPB;
        int s = ei[i];
        int d = ei[N_EDGES + i];
        int pos = row_start[d] + (int)cnt[(size_t)b * N_NODES + d] + (int)lrank[i];
        csr[pos] = (unsigned short)s;
    }
}

// ---------------- P4+P5 fused: aggregate 16-node tile in LDS, MFMA lin ----------
// 625 blocks x 256 threads (4 waves). Wave w aggregates nodes row0+w*4..+3
// (4 slots x 16 feature-octets per node, shuffle reduce), packs bf16 into
// atile[16][136]. Then each wave does 2 F-tiles of 16x16 MFMA (A-agg from LDS,
// A-x from global xh, B = W rows). Verified layouts (R11 passed correctness).

__global__ __launch_bounds__(256) void agg_lin_kernel(const float* __restrict__ x,
                                                      const unsigned short* __restrict__ xh,
                                                      const int* __restrict__ row_start,
                                                      const unsigned short* __restrict__ csr,
                                                      const unsigned short* __restrict__ Wlb,
                                                      const unsigned short* __restrict__ Wrb,
                                                      const float* __restrict__ bl,
                                                      float* __restrict__ out) {
    __shared__ __align__(16) unsigned short atile[16][136];   // 272B row stride
    const int tid = threadIdx.x;
    const int wave = tid >> 6;
    const int lane = tid & 63;
    const int slot = lane >> 4;        // 0..3
    const int lane16 = lane & 15;      // feature octet
    const int row0 = blockIdx.x * 16;
    const us8* xh8 = (const us8*)xh;

    // ---- aggregation: 4 nodes per wave ----
#pragma unroll
    for (int q = 0; q < 4; ++q) {
        const int node = row0 + wave * 4 + q;
        const int start = row_start[node];
        const int end = row_start[node + 1];
        f32x8 a0 = 0.f, a1 = 0.f, a2 = 0.f, a3 = 0.f;
        int j = start + slot;
        for (; j + 12 < end; j += 16) {
            int i0 = csr[j], i1 = csr[j + 4], i2 = csr[j + 8], i3 = csr[j + 12];
            us8 v0 = xh8[i0 * 16 + lane16];
            us8 v1 = xh8[i1 * 16 + lane16];
            us8 v2 = xh8[i2 * 16 + lane16];
            us8 v3 = xh8[i3 * 16 + lane16];
            a0 += bf2f8(v0); a1 += bf2f8(v1); a2 += bf2f8(v2); a3 += bf2f8(v3);
        }
        for (; j < end; j += 4) a0 += bf2f8(xh8[(int)csr[j] * 16 + lane16]);
        a0 = (a0 + a1) + (a2 + a3);
#pragma unroll
        for (int c = 0; c < 8; ++c) {
            float v = a0[c];
            v += __shfl_xor(v, 16, 64);
            v += __shfl_xor(v, 32, 64);
            a0[c] = v;
        }
        if (slot == 0) {
            int cntE = end - start;
            float inv = (cntE > 0) ? 1.0f / (float)cntE : 0.0f;
            us8 pack;
#pragma unroll
            for (int t = 0; t < 8; ++t) pack[t] = f2bf(a0[t] * inv);
            *(us8*)&atile[wave * 4 + q][lane16 * 8] = pack;
        }
    }
    __syncthreads();

    // ---- MFMA lin: 8 F-tiles over 4 waves ----
    const int l15 = lane & 15;
    const int quad = lane >> 4;
    const int m = row0 + l15;
    const bf16x8* xrow = (const bf16x8*)(xh + (size_t)m * D) + quad;

    for (int ft = wave; ft < 8; ft += 4) {
        const int out0 = ft * 16;
        const int f = out0 + l15;
        const bf16x8* wlro = (const bf16x8*)(Wlb + (size_t)f * D) + quad;
        const bf16x8* wrro = (const bf16x8*)(Wrb + (size_t)f * D) + quad;

        f32x4 c = {0.f, 0.f, 0.f, 0.f};
#pragma unroll
        for (int kk = 0; kk < 4; ++kk) {
            bf16x8 afrag = *(const bf16x8*)&atile[l15][quad * 8 + kk * 32];
            c = __builtin_amdgcn_mfma_f32_16x16x32_bf16(afrag, wlro[kk * 4], c, 0, 0, 0);
            c = __builtin_amdgcn_mfma_f32_16x16x32_bf16(xrow[kk * 4], wrro[kk * 4], c, 0, 0, 0);
        }

        const float bias = bl[f];
#pragma unroll
        for (int r = 0; r < 4; ++r) {
            int row = row0 + quad * 4 + r;
            int idx = row * D + f;
            out[idx] = x[idx] + bias + c[r];
        }
    }
}

extern "C" void kernel_launch(void* const* d_in, const int* in_sizes, int n_in,
                              void* d_out, int out_size, void* d_ws, size_t ws_size,
                              hipStream_t stream) {
    const float* x  = (const float*)d_in[0];
    const int*   ei = (const int*)d_in[1];     // [2, E] int32
    const float* Wl = (const float*)d_in[2];
    const float* bl = (const float*)d_in[3];
    const float* Wr = (const float*)d_in[4];
    float* out = (float*)d_out;

    // workspace layout (16B-aligned segments)
    unsigned long long* flags = (unsigned long long*)d_ws;               // 64 ULL
    int* row_start = (int*)(flags + 64);                                 // 10016 ints
    unsigned short* cnt   = (unsigned short*)(row_start + 10016);        // NB*N_NODES us
    unsigned short* lrank = cnt + (size_t)NB * N_NODES;                  // N_EDGES us
    unsigned short* csr   = lrank + N_EDGES;                             // N_EDGES us
    unsigned short* xh    = csr + N_EDGES;                               // N_NODES*D bf16
    unsigned short* Wlb   = xh + (size_t)N_NODES * D;                    // D*D bf16
    unsigned short* Wrb   = Wlb + D * D;                                 // D*D bf16

    hist_cast_kernel<<<NB, HTHR, 0, stream>>>(ei, (const float4*)x, (const float4*)Wl,
                                              (const float4*)Wr, (ushort4*)xh,
                                              (ushort4*)Wlb, (ushort4*)Wrb,
                                              lrank, cnt, flags);
    colscan_scan_kernel<<<SB, 256, 0, stream>>>(cnt, row_start, flags);
    scatter_kernel<<<(N_EDGES + 255) / 256, 256, 0, stream>>>(ei, row_start, cnt, lrank, csr);
    agg_lin_kernel<<<N_NODES / 16, 256, 0, stream>>>(x, xh, row_start, csr,
                                                     Wlb, Wrb, bl, out);
}